// Round 9
// baseline (105.688 us; speedup 1.0000x reference)
//
#include <hip/hip_runtime.h>

// SKA: per-pixel dynamic depthwise 5x5 conv
// x: [B=8, C=256, H=64, W=64] f32
// w: [B=8, G=8, K2=25, H=64, W=64] f32
// out[b,c,h,w] = sum_k x[b,c,h+k/5-2,w+k%5-2] * w[b,g,k,h,w], g = c/32
//
// Design P2b (round 16): P2 + no-drain barriers. SINGLE variable change.
// Round-15 post-mortem: P2 (2-deep prefetch, 2 blocks/CU) = ~29.6us vs
// ~20us HBM-bound floor. The 2-deep prefetch is defeated by __syncthreads:
// hipcc emits s_waitcnt vmcnt(0) lgkmcnt(0) before s_barrier (documented,
// m97 asm) -> EVERY chunk barrier drains the chunk-i+2 prefetch loads and
// the output stores. Under HBM contention (prologue bursts 280KB/CU) load
// latency >> 900cyc, so all 4 waves stall at each barrier for loads that
// aren't needed until next chunk. Shared serializer of H3/H4/H5/P/P2.
// Fix: counted-wait barrier (8-phase template pattern, m201-verified):
//   s_waitcnt lgkmcnt(0)   ; my ds_writes committed -> LDS visible to block
//   s_barrier              ; raw barrier, NO vmcnt drain
// Global loads stay in flight across barriers (vmcnt waits happen at their
// consumers, one chunk later); stores never drained. WAR on buffer reuse
// safe: lgkmcnt(0) also retires this wave's COMPUTE ds_reads, and those
// precede its STAGE writes in program+pipe order.
// Keep from P2 (frozen): 2-deep chunk prefetch (rA/rB), 2 blocks/CU
// (grid 512, half-group per block), w fully VGPR-resident (25 quads,
// loaded once raw), PITCH=66 (b64 4-addr/bank floor), staged-zero OOB rows
// (exact jnp.pad semantics), zeroed guards/pads, stores after barrier,
// 4-chunk full unroll (static indexing).
// Tripwires: VGPR ~190-215, WRITE_SIZE ~33MB. Decision rule: >=3us gain =>
// drain theory confirmed -> next: full-group 8-row-band blocks (w dup
// 52->26MB, prologue 280->150KB/CU). Flat => drain theory dead, same pivot.

#define B_ 8
#define C_ 256
#define G_ 8
#define CG_ 32
#define H_ 64
#define W_ 64
#define K2_ 25
#define HW_ (H_ * W_)
#define NCH 4               // channels per chunk
#define NCHUNK 4            // chunks per block (half group = 16 channels)
#define NROWS 20            // 16-row band + 2 halo each side
#define PITCH 66            // 64 data + 2 pad words; stride == 2 mod 32 banks
#define CHSTRIDE 1322       // 2 guard words + 20*66
#define BUFW (NCH * CHSTRIDE)  // 5288 words = 21.2 KB per buffer

// no-drain block barrier: commit my LDS writes, then raw s_barrier.
// (__syncthreads would add s_waitcnt vmcnt(0) = full VMEM drain.)
#define BARRIER_NODRAIN()                                \
  {                                                      \
    asm volatile("s_waitcnt lgkmcnt(0)" ::: "memory");   \
    __builtin_amdgcn_s_barrier();                        \
  }

#define ISSUE(R0, R1, R2, R3, R4, CH)                    \
  {                                                      \
    const float* xn = xg + (size_t)(CH) * NCH * HW_;     \
    R0 = *(const float4*)(xn + soff[0]);                 \
    R1 = *(const float4*)(xn + soff[1]);                 \
    R2 = *(const float4*)(xn + soff[2]);                 \
    R3 = *(const float4*)(xn + soff[3]);                 \
    R4 = *(const float4*)(xn + soff[4]);                 \
  }

// OOB rows staged as exact 0 (= jnp.pad); cndmask consumes loads right at
// the ds_write, which is where the vmcnt wait belongs anyway.
#define STAGE(R0, R1, R2, R3, R4, PB)                                     \
  {                                                                       \
    const float4 z4 = make_float4(0.f, 0.f, 0.f, 0.f);                    \
    const float4 v0 = sok[0] ? R0 : z4;                                   \
    const float4 v1 = sok[1] ? R1 : z4;                                   \
    const float4 v2 = sok[2] ? R2 : z4;                                   \
    const float4 v3 = sok[3] ? R3 : z4;                                   \
    const float4 v4 = sok[4] ? R4 : z4;                                   \
    *(float2*)&lds[(PB) + swo[0]] = make_float2(v0.x, v0.y);              \
    *(float2*)&lds[(PB) + swo[0] + 2] = make_float2(v0.z, v0.w);          \
    *(float2*)&lds[(PB) + swo[1]] = make_float2(v1.x, v1.y);              \
    *(float2*)&lds[(PB) + swo[1] + 2] = make_float2(v1.z, v1.w);          \
    *(float2*)&lds[(PB) + swo[2]] = make_float2(v2.x, v2.y);              \
    *(float2*)&lds[(PB) + swo[2] + 2] = make_float2(v2.z, v2.w);          \
    *(float2*)&lds[(PB) + swo[3]] = make_float2(v3.x, v3.y);              \
    *(float2*)&lds[(PB) + swo[3] + 2] = make_float2(v3.z, v3.w);          \
    *(float2*)&lds[(PB) + swo[4]] = make_float2(v4.x, v4.y);              \
    *(float2*)&lds[(PB) + swo[4] + 2] = make_float2(v4.z, v4.w);          \
  }

// compute NCH channel quads from buf at word offset PB into acc[][]
#define COMPUTE(PB)                                                       \
  _Pragma("unroll") for (int c = 0; c < NCH; ++c) {                       \
    acc[c][0] = 0.f; acc[c][1] = 0.f; acc[c][2] = 0.f; acc[c][3] = 0.f;   \
  }                                                                       \
  _Pragma("unroll") for (int di = 0; di < 5; ++di) {                      \
    const int rbase = (PB) + (lr + di) * PITCH + wcol;                    \
    _Pragma("unroll") for (int c = 0; c < NCH; ++c) {                     \
      const int a0 = c * CHSTRIDE + rbase;                                \
      alignas(16) float xr[8];                                            \
      *(float2*)&xr[0] = *(const float2*)&lds[a0];                        \
      *(float2*)&xr[2] = *(const float2*)&lds[a0 + 2];                    \
      *(float2*)&xr[4] = *(const float2*)&lds[a0 + 4];                    \
      *(float2*)&xr[6] = *(const float2*)&lds[a0 + 6];                    \
      _Pragma("unroll") for (int dj = 0; dj < 5; ++dj) {                  \
        const float4 wv = wk[di * 5 + dj];                                \
        acc[c][0] = fmaf(xr[dj + 0], wv.x, acc[c][0]);                    \
        acc[c][1] = fmaf(xr[dj + 1], wv.y, acc[c][1]);                    \
        acc[c][2] = fmaf(xr[dj + 2], wv.z, acc[c][2]);                    \
        acc[c][3] = fmaf(xr[dj + 3], wv.w, acc[c][3]);                    \
      }                                                                   \
    }                                                                     \
  }

#define STORE(CH)                                                         \
  {                                                                       \
    float* ob = og + (size_t)(CH) * NCH * HW_;                            \
    *(float4*)(ob + (size_t)0 * HW_) = *(const float4*)acc[0];            \
    *(float4*)(ob + (size_t)1 * HW_) = *(const float4*)acc[1];            \
    *(float4*)(ob + (size_t)2 * HW_) = *(const float4*)acc[2];            \
    *(float4*)(ob + (size_t)3 * HW_) = *(const float4*)acc[3];            \
  }

__global__ __launch_bounds__(256, 2) void ska_kernel(
    const float* __restrict__ x, const float* __restrict__ w,
    float* __restrict__ out) {
  __shared__ __align__(16) float lds[2 * BUFW];  // 41.3 KB
  const int tid = threadIdx.x;
  const int lr = tid >> 4;   // output row within band (0..15)
  const int j = tid & 15;    // column quad (cols 4j..4j+3)
  const int wcol = j * 4;

  // blockIdx = [half(1) | b(3) | g(3) | band(2)], 512 blocks = 2 per CU.
  const int blk = blockIdx.x;
  const int band = blk & 3;
  const int g = (blk >> 2) & 7;
  const int b = (blk >> 5) & 7;
  const int half = blk >> 8;  // 0/1: which 16 channels of the group

  const int h0 = band * 16;
  const int h = h0 + lr;

  // ---- chunk-invariant staging slots: 5 per thread ----
  int soff[5];   // x word offset within chunk (c*HW + clamped_row*W + q*4)
  int swo[5];    // LDS word offset within buffer
  bool sok[5];   // row in bounds?
#pragma unroll
  for (int it = 0; it < 5; ++it) {
    const int i = tid + it * 256;
    const int c = i / 320;            // magic-mul
    const int rem = i - c * 320;
    const int rl = rem >> 4;          // window row 0..19
    const int q = rem & 15;           // column quad
    const int gr = h0 - 2 + rl;       // global row, may be OOB
    sok[it] = (unsigned)gr < (unsigned)H_;
    const int grc = min(max(gr, 0), H_ - 1);
    soff[it] = c * HW_ + grc * W_ + q * 4;
    swo[it] = c * CHSTRIDE + 2 + rl * PITCH + q * 4;  // 8B aligned
  }

  // ---- zero guards (2/ch) + row pads (2/row): 42 words x 4 ch, BOTH bufs ----
  if (tid < NCH * 42) {
    const int c = tid / 42;
    const int p = tid - c * 42;
    const int word =
        (p < 2) ? p : (2 + ((p - 2) >> 1) * PITCH + 64 + ((p - 2) & 1));
    lds[c * CHSTRIDE + word] = 0.0f;
    lds[BUFW + c * CHSTRIDE + word] = 0.0f;
  }

  const size_t chanbase = (size_t)(b * C_ + g * CG_ + half * 16) * HW_;
  const float* xg = x + chanbase;
  float* og = out + chanbase + (size_t)h * W_ + wcol;

  // ---- prologue: issue chunk 0 AND chunk 1 loads (2-deep from the start) ----
  float4 a0, a1, a2, a3, a4;   // reg set A
  float4 b0, b1, b2, b3, b4;   // reg set B
  ISSUE(a0, a1, a2, a3, a4, 0)
  ISSUE(b0, b1, b2, b3, b4, 1)

  // ---- load ALL 25 weight quads RAW, once (VGPR-resident all kernel) ----
  const float* wb =
      w + (size_t)(b * G_ + g) * K2_ * HW_ + (size_t)h * W_ + wcol;
  float4 wk[K2_];
#pragma unroll
  for (int k = 0; k < K2_; ++k)
    wk[k] = *(const float4*)(wb + (size_t)k * HW_);

  STAGE(a0, a1, a2, a3, a4, 0)   // chunk 0 -> buf0 (waits only chunk-0 loads)
  BARRIER_NODRAIN()

  alignas(16) float acc[NCH][4];

  // ---- chunk 0: issue L2 into A; compute buf0; stage chunk1 -> buf1 ----
  ISSUE(a0, a1, a2, a3, a4, 2)
  COMPUTE(0)
  STAGE(b0, b1, b2, b3, b4, BUFW)
  BARRIER_NODRAIN()
  STORE(0)

  // ---- chunk 1: issue L3 into B; compute buf1; stage chunk2 -> buf0 ----
  ISSUE(b0, b1, b2, b3, b4, 3)
  COMPUTE(BUFW)
  STAGE(a0, a1, a2, a3, a4, 0)
  BARRIER_NODRAIN()
  STORE(1)

  // ---- chunk 2: compute buf0; stage chunk3 -> buf1 ----
  COMPUTE(0)
  STAGE(b0, b1, b2, b3, b4, BUFW)
  BARRIER_NODRAIN()
  STORE(2)

  // ---- chunk 3: compute buf1; store ----
  COMPUTE(BUFW)
  STORE(3)
}

extern "C" void kernel_launch(void* const* d_in, const int* in_sizes, int n_in,
                              void* d_out, int out_size, void* d_ws,
                              size_t ws_size, hipStream_t stream) {
  const float* x = (const float*)d_in[0];
  const float* w = (const float*)d_in[1];
  float* out = (float*)d_out;
  // grid: 2 halves * 8 b * 8 g * 4 bands = 512 blocks of 256 threads
  ska_kernel<<<dim3(512), dim3(256), 0, stream>>>(x, w, out);
}